// Round 1
// baseline (638.545 us; speedup 1.0000x reference)
//
#include <hip/hip_runtime.h>

#define BLOCK 512
#define RPB   128          // rows per chunk (block)
#define NU    32           // u-values per half-sweep

// x1 staged feature-major: element (fl, row) at lds_x1[fl*128 + (row ^ swz(fl))]
// XOR swizzle keeps transpose-writes to <=4-way bank conflict; reads stay aligned b128.
__device__ __forceinline__ int swz(int fl) { return ((fl >> 2) & 7) << 2; }

__global__ __launch_bounds__(BLOCK, 2) void tp_kernel(
    const float* __restrict__ x1, const float* __restrict__ x2,
    const float* __restrict__ w0, const float* __restrict__ w1,
    const float* __restrict__ w2, const float* __restrict__ w3,
    const float* __restrict__ w4,
    float* __restrict__ out, int n)
{
    __shared__ __align__(16) float lds_w[5 * 4096];    // 80 KB, natural [u][w]
    __shared__ __align__(16) float lds_x1[128 * 128];  // 64 KB, feature-major swizzled half-tile
    __shared__ float lds_x2[RPB * 4];                  // 2 KB

    const int t = threadIdx.x;

    // ---- stage all 5 weight matrices (once per block) ----
    {
        const float* srcs[5] = {w0, w1, w2, w3, w4};
        #pragma unroll
        for (int m = 0; m < 5; ++m) {
            const float4* s = (const float4*)srcs[m];
            float4* d = (float4*)(&lds_w[m * 4096]);
            for (int i = t; i < 1024; i += BLOCK) d[i] = s[i];
        }
    }

    const int g  = t & 15;          // output column group: w = 4g..4g+3
    const int r0 = (t >> 4) * 4;    // first of this thread's 4 rows (0..124)
    const int z0 = blockIdx.x * RPB;

    // ---- accumulators: 4 rows x 4 cols x 11 = 176 VGPRs ----
    float yss[4][4], ysv[4][4], yvvs[4][4][3], yvs[4][4][3], yvvv[4][4][3];
    #pragma unroll
    for (int r = 0; r < 4; ++r)
        #pragma unroll
        for (int j = 0; j < 4; ++j) {
            yss[r][j] = 0.f; ysv[r][j] = 0.f;
            #pragma unroll
            for (int i = 0; i < 3; ++i) { yvvs[r][j][i] = 0.f; yvs[r][j][i] = 0.f; yvvv[r][j][i] = 0.f; }
        }

    const float* lw0 = lds_w + 0*4096 + 4*g;
    const float* lw1 = lds_w + 1*4096 + 4*g;
    const float* lw2 = lds_w + 2*4096 + 4*g;
    const float* lw3 = lds_w + 3*4096 + 4*g;
    const float* lw4 = lds_w + 4*4096 + 4*g;

    for (int h = 0; h < 2; ++h) {
        if (h) __syncthreads();   // previous half's compute must finish before restage

        // ---- stage half of x1, transposed to feature-major ----
        // local features fl = 0..31  -> global cols [32h, 32h+32)          (scalars)
        //                fl = 32..127 -> global cols [64+96h, 64+96h+96)    (vectors)
        for (int i = t; i < 128 * 32; i += BLOCK) {
            const int row = i >> 5;
            const int c4  = i & 31;
            const int z   = z0 + row;
            float4 v = make_float4(0.f, 0.f, 0.f, 0.f);
            if (z < n) {
                const float* src = (c4 < 8)
                    ? (x1 + (size_t)z * 256 + h * NU + 4 * c4)
                    : (x1 + (size_t)z * 256 + 64 + 96 * h + 4 * (c4 - 8));
                v = *(const float4*)src;
            }
            const int fl = 4 * c4;                 // fl..fl+3 share swz (same fl>>2)
            const int p  = row ^ swz(fl);
            lds_x1[(fl + 0) * 128 + p] = v.x;
            lds_x1[(fl + 1) * 128 + p] = v.y;
            lds_x1[(fl + 2) * 128 + p] = v.z;
            lds_x1[(fl + 3) * 128 + p] = v.w;
        }
        if (h == 0) {
            const int z = z0 + (t >> 2);
            lds_x2[t] = (z < n) ? x2[(size_t)z * 4 + (t & 3)] : 0.f;
        }
        __syncthreads();

        // ---- half u-sweep: 9 x ds_read_b128, 176 FMAs per u ----
        const int ub = h * NU * 64;   // weight float offset for this half
        for (int uu = 0; uu < NU; ++uu) {
            float4 wss  = *(const float4*)(lw0 + ub + uu * 64);
            float4 wvvs = *(const float4*)(lw1 + ub + uu * 64);
            float4 wsv  = *(const float4*)(lw2 + ub + uu * 64);
            float4 wvs  = *(const float4*)(lw3 + ub + uu * 64);
            float4 wvvv = *(const float4*)(lw4 + ub + uu * 64);

            float4 s1  = *(const float4*)(lds_x1 + uu * 128        + (r0 ^ swz(uu)));
            const int f0 = 32 + 3 * uu;
            float4 v1x = *(const float4*)(lds_x1 + (f0 + 0) * 128 + (r0 ^ swz(f0 + 0)));
            float4 v1y = *(const float4*)(lds_x1 + (f0 + 1) * 128 + (r0 ^ swz(f0 + 1)));
            float4 v1z = *(const float4*)(lds_x1 + (f0 + 2) * 128 + (r0 ^ swz(f0 + 2)));

            const float* wssf  = (const float*)&wss;
            const float* wvvsf = (const float*)&wvvs;
            const float* wsvf  = (const float*)&wsv;
            const float* wvsf  = (const float*)&wvs;
            const float* wvvvf = (const float*)&wvvv;
            const float* s1f   = (const float*)&s1;
            const float* v1xf  = (const float*)&v1x;
            const float* v1yf  = (const float*)&v1y;
            const float* v1zf  = (const float*)&v1z;

            #pragma unroll
            for (int r = 0; r < 4; ++r) {
                const float s  = s1f[r];
                const float vx = v1xf[r];
                const float vy = v1yf[r];
                const float vz = v1zf[r];
                #pragma unroll
                for (int j = 0; j < 4; ++j) {
                    yss[r][j]     += wssf[j]  * s;
                    ysv[r][j]     += wsvf[j]  * s;
                    yvvs[r][j][0] += wvvsf[j] * vx;
                    yvvs[r][j][1] += wvvsf[j] * vy;
                    yvvs[r][j][2] += wvvsf[j] * vz;
                    yvs[r][j][0]  += wvsf[j]  * vx;
                    yvs[r][j][1]  += wvsf[j]  * vy;
                    yvs[r][j][2]  += wvsf[j]  * vz;
                    yvvv[r][j][0] += wvvvf[j] * vx;
                    yvvv[r][j][1] += wvvvf[j] * vy;
                    yvvv[r][j][2] += wvvvf[j] * vz;
                }
            }
        }
    }

    // ---- epilogue: fold in x2, write 4 rows ----
    const float a0  = 0.088388347648318447f;   // sqrt(1/(2*64))
    const float a1  = 0.072168783648703216f;   // sqrt(1/(3*64))
    const float is3 = 0.57735026918962576f;    // 1/sqrt(3)
    const float is2 = 0.70710678118654752f;    // 1/sqrt(2)
    #pragma unroll
    for (int k = 0; k < 4; ++k) {
        const int row = r0 + k;
        const int z   = z0 + row;
        if (z >= n) continue;
        const float s2  = lds_x2[row * 4 + 0];
        const float v2x = lds_x2[row * 4 + 1];
        const float v2y = lds_x2[row * 4 + 2];
        const float v2z = lds_x2[row * 4 + 3];
        float* orow = out + (size_t)z * 256;
        alignas(16) float os[4];
        alignas(16) float ov[12];
        #pragma unroll
        for (int j = 0; j < 4; ++j) {
            os[j] = a0 * (yss[k][j] * s2
                  + is3 * (yvvs[k][j][0] * v2x + yvvs[k][j][1] * v2y + yvvs[k][j][2] * v2z));
            const float cx = yvvv[k][j][1] * v2z - yvvv[k][j][2] * v2y;
            const float cy = yvvv[k][j][2] * v2x - yvvv[k][j][0] * v2z;
            const float cz = yvvv[k][j][0] * v2y - yvvv[k][j][1] * v2x;
            ov[3*j+0] = a1 * (ysv[k][j] * v2x + yvs[k][j][0] * s2 + is2 * cx);
            ov[3*j+1] = a1 * (ysv[k][j] * v2y + yvs[k][j][1] * s2 + is2 * cy);
            ov[3*j+2] = a1 * (ysv[k][j] * v2z + yvs[k][j][2] * s2 + is2 * cz);
        }
        *(float4*)(orow + 4*g)           = *(float4*)os;
        *(float4*)(orow + 64 + 12*g + 0) = *(float4*)(ov + 0);
        *(float4*)(orow + 64 + 12*g + 4) = *(float4*)(ov + 4);
        *(float4*)(orow + 64 + 12*g + 8) = *(float4*)(ov + 8);
    }
}

extern "C" void kernel_launch(void* const* d_in, const int* in_sizes, int n_in,
                              void* d_out, int out_size, void* d_ws, size_t ws_size,
                              hipStream_t stream) {
    const float* x1 = (const float*)d_in[0];
    const float* x2 = (const float*)d_in[1];
    const float* w0 = (const float*)d_in[2];   // w_ss_s
    const float* w1 = (const float*)d_in[3];   // w_vv_s
    const float* w2 = (const float*)d_in[4];   // w_sv_v
    const float* w3 = (const float*)d_in[5];   // w_vs_v
    const float* w4 = (const float*)d_in[6];   // w_vv_v
    float* out = (float*)d_out;
    const int n = in_sizes[0] / 256;
    const int nchunks = (n + RPB - 1) / RPB;
    tp_kernel<<<nchunks, BLOCK, 0, stream>>>(x1, x2, w0, w1, w2, w3, w4, out, n);
}

// Round 2
// 626.287 us; speedup vs baseline: 1.0196x; 1.0196x over previous
//
#include <hip/hip_runtime.h>

#define BLOCK 512
#define RPB   128          // rows per chunk (block)
#define NU    32           // u-values per half-sweep

// x1 staged feature-major: element (fl, row) at lds_x1[fl*128 + (row ^ swz(fl))]
// swz keeps reads aligned-b128 (low 2 bits zero); staging lane remap makes writes conflict-free.
__device__ __forceinline__ int swz(int fl) { return ((fl >> 2) & 7) << 2; }

__global__ __launch_bounds__(BLOCK) void tp_kernel(
    const float* __restrict__ x1, const float* __restrict__ x2,
    const float* __restrict__ w0, const float* __restrict__ w1,
    const float* __restrict__ w2, const float* __restrict__ w3,
    const float* __restrict__ w4,
    float* __restrict__ out, int n)
{
    __shared__ __align__(16) float lds_w[5 * 4096];    // 80 KB, natural [u][w]
    __shared__ __align__(16) float lds_x1[128 * 128];  // 64 KB, feature-major swizzled half-tile
    __shared__ float lds_x2[RPB * 4];                  // 2 KB

    const int t = threadIdx.x;

    // ---- stage all 5 weight matrices (once per block) ----
    {
        const float* srcs[5] = {w0, w1, w2, w3, w4};
        #pragma unroll
        for (int m = 0; m < 5; ++m) {
            const float4* s = (const float4*)srcs[m];
            float4* d = (float4*)(&lds_w[m * 4096]);
            for (int i = t; i < 1024; i += BLOCK) d[i] = s[i];
        }
    }

    const int g  = t & 15;          // output column group: w = 4g..4g+3
    const int r0 = (t >> 4) * 4;    // first of this thread's 4 rows (0..124)
    const int z0 = blockIdx.x * RPB;

    // ---- accumulators: 4 rows x 4 cols x 11 = 176 VGPRs ----
    float yss[4][4], ysv[4][4], yvvs[4][4][3], yvs[4][4][3], yvvv[4][4][3];
    #pragma unroll
    for (int r = 0; r < 4; ++r)
        #pragma unroll
        for (int j = 0; j < 4; ++j) {
            yss[r][j] = 0.f; ysv[r][j] = 0.f;
            #pragma unroll
            for (int i = 0; i < 3; ++i) { yvvs[r][j][i] = 0.f; yvs[r][j][i] = 0.f; yvvv[r][j][i] = 0.f; }
        }

    const float* lw0 = lds_w + 0*4096 + 4*g;
    const float* lw1 = lds_w + 1*4096 + 4*g;
    const float* lw2 = lds_w + 2*4096 + 4*g;
    const float* lw3 = lds_w + 3*4096 + 4*g;
    const float* lw4 = lds_w + 4*4096 + 4*g;

    for (int h = 0; h < 2; ++h) {
        if (h) __syncthreads();   // previous half's compute must finish before restage

        // ---- stage half of x1, transposed to feature-major ----
        // lane remap: 64 consecutive i cover 8 rows x 8 feature-quads
        //  -> write banks (row ^ (c4&7)<<2) span all 32 banks (conflict-free)
        //  -> global reads: 8 lanes x 16B contiguous per row segment
        // local features fl = 0..31   -> global cols [32h, 32h+32)        (scalars)
        //                fl = 32..127 -> global cols [64+96h, 64+96h+96)  (vectors)
        for (int i = t; i < 128 * 32; i += BLOCK) {
            const int l   = i & 63;
            const int blk = i >> 6;
            const int c4  = (l & 7) + ((blk & 3) << 3);        // 0..31
            const int row = (l >> 3) + ((blk >> 2) << 3);      // 0..127
            const int z   = z0 + row;
            float4 v = make_float4(0.f, 0.f, 0.f, 0.f);
            if (z < n) {
                const float* src = (c4 < 8)
                    ? (x1 + (size_t)z * 256 + h * NU + 4 * c4)
                    : (x1 + (size_t)z * 256 + 64 + 96 * h + 4 * (c4 - 8));
                v = *(const float4*)src;
            }
            const int fl = 4 * c4;                 // fl..fl+3 share swz (same fl>>2)
            const int p  = row ^ swz(fl);
            lds_x1[(fl + 0) * 128 + p] = v.x;
            lds_x1[(fl + 1) * 128 + p] = v.y;
            lds_x1[(fl + 2) * 128 + p] = v.z;
            lds_x1[(fl + 3) * 128 + p] = v.w;
        }
        if (h == 0) {
            const int z = z0 + (t >> 2);
            lds_x2[t] = (z < n) ? x2[(size_t)z * 4 + (t & 3)] : 0.f;
        }
        __syncthreads();

        // ---- half u-sweep: 9 x ds_read_b128, 176 FMAs per u ----
        const int ub = h * NU * 64;   // weight float offset for this half
        for (int uu = 0; uu < NU; ++uu) {
            float4 wss  = *(const float4*)(lw0 + ub + uu * 64);
            float4 wvvs = *(const float4*)(lw1 + ub + uu * 64);
            float4 wsv  = *(const float4*)(lw2 + ub + uu * 64);
            float4 wvs  = *(const float4*)(lw3 + ub + uu * 64);
            float4 wvvv = *(const float4*)(lw4 + ub + uu * 64);

            float4 s1  = *(const float4*)(lds_x1 + uu * 128        + (r0 ^ swz(uu)));
            const int f0 = 32 + 3 * uu;
            float4 v1x = *(const float4*)(lds_x1 + (f0 + 0) * 128 + (r0 ^ swz(f0 + 0)));
            float4 v1y = *(const float4*)(lds_x1 + (f0 + 1) * 128 + (r0 ^ swz(f0 + 1)));
            float4 v1z = *(const float4*)(lds_x1 + (f0 + 2) * 128 + (r0 ^ swz(f0 + 2)));

            const float* wssf  = (const float*)&wss;
            const float* wvvsf = (const float*)&wvvs;
            const float* wsvf  = (const float*)&wsv;
            const float* wvsf  = (const float*)&wvs;
            const float* wvvvf = (const float*)&wvvv;
            const float* s1f   = (const float*)&s1;
            const float* v1xf  = (const float*)&v1x;
            const float* v1yf  = (const float*)&v1y;
            const float* v1zf  = (const float*)&v1z;

            #pragma unroll
            for (int r = 0; r < 4; ++r) {
                const float s  = s1f[r];
                const float vx = v1xf[r];
                const float vy = v1yf[r];
                const float vz = v1zf[r];
                #pragma unroll
                for (int j = 0; j < 4; ++j) {
                    yss[r][j]     += wssf[j]  * s;
                    ysv[r][j]     += wsvf[j]  * s;
                    yvvs[r][j][0] += wvvsf[j] * vx;
                    yvvs[r][j][1] += wvvsf[j] * vy;
                    yvvs[r][j][2] += wvvsf[j] * vz;
                    yvs[r][j][0]  += wvsf[j]  * vx;
                    yvs[r][j][1]  += wvsf[j]  * vy;
                    yvs[r][j][2]  += wvsf[j]  * vz;
                    yvvv[r][j][0] += wvvvf[j] * vx;
                    yvvv[r][j][1] += wvvvf[j] * vy;
                    yvvv[r][j][2] += wvvvf[j] * vz;
                }
            }
        }
    }

    // ---- epilogue: fold in x2, write 4 rows ----
    const float a0  = 0.088388347648318447f;   // sqrt(1/(2*64))
    const float a1  = 0.072168783648703216f;   // sqrt(1/(3*64))
    const float is3 = 0.57735026918962576f;    // 1/sqrt(3)
    const float is2 = 0.70710678118654752f;    // 1/sqrt(2)
    #pragma unroll
    for (int k = 0; k < 4; ++k) {
        const int row = r0 + k;
        const int z   = z0 + row;
        if (z >= n) continue;
        const float s2  = lds_x2[row * 4 + 0];
        const float v2x = lds_x2[row * 4 + 1];
        const float v2y = lds_x2[row * 4 + 2];
        const float v2z = lds_x2[row * 4 + 3];
        float* orow = out + (size_t)z * 256;
        alignas(16) float os[4];
        alignas(16) float ov[12];
        #pragma unroll
        for (int j = 0; j < 4; ++j) {
            os[j] = a0 * (yss[k][j] * s2
                  + is3 * (yvvs[k][j][0] * v2x + yvvs[k][j][1] * v2y + yvvs[k][j][2] * v2z));
            const float cx = yvvv[k][j][1] * v2z - yvvv[k][j][2] * v2y;
            const float cy = yvvv[k][j][2] * v2x - yvvv[k][j][0] * v2z;
            const float cz = yvvv[k][j][0] * v2y - yvvv[k][j][1] * v2x;
            ov[3*j+0] = a1 * (ysv[k][j] * v2x + yvs[k][j][0] * s2 + is2 * cx);
            ov[3*j+1] = a1 * (ysv[k][j] * v2y + yvs[k][j][1] * s2 + is2 * cy);
            ov[3*j+2] = a1 * (ysv[k][j] * v2z + yvs[k][j][2] * s2 + is2 * cz);
        }
        *(float4*)(orow + 4*g)           = *(float4*)os;
        *(float4*)(orow + 64 + 12*g + 0) = *(float4*)(ov + 0);
        *(float4*)(orow + 64 + 12*g + 4) = *(float4*)(ov + 4);
        *(float4*)(orow + 64 + 12*g + 8) = *(float4*)(ov + 8);
    }
}

extern "C" void kernel_launch(void* const* d_in, const int* in_sizes, int n_in,
                              void* d_out, int out_size, void* d_ws, size_t ws_size,
                              hipStream_t stream) {
    const float* x1 = (const float*)d_in[0];
    const float* x2 = (const float*)d_in[1];
    const float* w0 = (const float*)d_in[2];   // w_ss_s
    const float* w1 = (const float*)d_in[3];   // w_vv_s
    const float* w2 = (const float*)d_in[4];   // w_sv_v
    const float* w3 = (const float*)d_in[5];   // w_vs_v
    const float* w4 = (const float*)d_in[6];   // w_vv_v
    float* out = (float*)d_out;
    const int n = in_sizes[0] / 256;
    const int nchunks = (n + RPB - 1) / RPB;
    tp_kernel<<<nchunks, BLOCK, 0, stream>>>(x1, x2, w0, w1, w2, w3, w4, out, n);
}

// Round 3
// 622.284 us; speedup vs baseline: 1.0261x; 1.0064x over previous
//
#include <hip/hip_runtime.h>

#define BLOCK 512
#define RPG   32          // rows per group: 512 threads = 32 rows x 16 col-groups

__global__ __launch_bounds__(BLOCK, 4) void tp_kernel(
    const float* __restrict__ x1, const float* __restrict__ x2,
    const float* __restrict__ w0, const float* __restrict__ w1,
    const float* __restrict__ w2, const float* __restrict__ w3,
    const float* __restrict__ w4,
    float* __restrict__ out, int n)
{
    // Weights ONLY in LDS: 81920 B exactly -> 2 blocks/CU (16 waves, 4/SIMD).
    // x1 is streamed via global loads: the 16 lanes sharing a row are consecutive
    // lanes of one wave, so same-address loads broadcast (no LDS staging needed).
    __shared__ __align__(16) float lds_w[5 * 4096];

    const int t = threadIdx.x;

    {   // ---- stage all 5 weight matrices once per block ----
        const float* srcs[5] = {w0, w1, w2, w3, w4};
        #pragma unroll
        for (int m = 0; m < 5; ++m) {
            const float4* s = (const float4*)srcs[m];
            float4* d = (float4*)(&lds_w[m * 4096]);
            for (int i = t; i < 1024; i += BLOCK) d[i] = s[i];
        }
    }
    __syncthreads();   // the ONLY barrier in the kernel

    const int g = t & 15;    // output column group: w = 4g..4g+3
    const int r = t >> 4;    // row within group: 0..31

    const float a0  = 0.088388347648318447f;   // sqrt(1/(2*64))
    const float a1  = 0.072168783648703216f;   // sqrt(1/(3*64))
    const float is3 = 0.57735026918962576f;    // 1/sqrt(3)
    const float is2 = 0.70710678118654752f;    // 1/sqrt(2)

    const int ngroups = (n + RPG - 1) / RPG;
    for (int grp = blockIdx.x; grp < ngroups; grp += (int)gridDim.x) {
        const int z   = grp * RPG + r;
        const bool act = (z < n);
        const float* xrow = x1 + (size_t)(act ? z : 0) * 256;  // clamp: safe dummy row

        float yss[4], ysv[4], yvvs[4][3], yvs[4][3], yvvv[4][3];
        #pragma unroll
        for (int j = 0; j < 4; ++j) {
            yss[j] = 0.f; ysv[j] = 0.f;
            #pragma unroll
            for (int i = 0; i < 3; ++i) { yvvs[j][i] = 0.f; yvs[j][i] = 0.f; yvvv[j][i] = 0.f; }
        }

        // ---- stream x1 row through registers in 8-u chunks ----
        #pragma unroll 1
        for (int uc = 0; uc < 8; ++uc) {
            alignas(16) float sarr[8];    // scalars u = 8uc .. 8uc+7
            alignas(16) float varr[24];   // vectors (u,i), i fastest
            *(float4*)(sarr + 0) = *(const float4*)(xrow + uc * 8 + 0);
            *(float4*)(sarr + 4) = *(const float4*)(xrow + uc * 8 + 4);
            #pragma unroll
            for (int k = 0; k < 6; ++k)
                *(float4*)(varr + 4 * k) = *(const float4*)(xrow + 64 + uc * 24 + 4 * k);

            #pragma unroll
            for (int q = 0; q < 8; ++q) {
                const int u = uc * 8 + q;
                const float4 wss  = *(const float4*)(&lds_w[0 * 4096 + u * 64 + 4 * g]);
                const float4 wvvs = *(const float4*)(&lds_w[1 * 4096 + u * 64 + 4 * g]);
                const float4 wsv  = *(const float4*)(&lds_w[2 * 4096 + u * 64 + 4 * g]);
                const float4 wvs  = *(const float4*)(&lds_w[3 * 4096 + u * 64 + 4 * g]);
                const float4 wvvv = *(const float4*)(&lds_w[4 * 4096 + u * 64 + 4 * g]);

                const float s  = sarr[q];
                const float vx = varr[3 * q + 0];
                const float vy = varr[3 * q + 1];
                const float vz = varr[3 * q + 2];

                const float* wssf  = (const float*)&wss;
                const float* wvvsf = (const float*)&wvvs;
                const float* wsvf  = (const float*)&wsv;
                const float* wvsf  = (const float*)&wvs;
                const float* wvvvf = (const float*)&wvvv;

                #pragma unroll
                for (int j = 0; j < 4; ++j) {
                    yss[j]     += wssf[j]  * s;
                    ysv[j]     += wsvf[j]  * s;
                    yvvs[j][0] += wvvsf[j] * vx;
                    yvvs[j][1] += wvvsf[j] * vy;
                    yvvs[j][2] += wvvsf[j] * vz;
                    yvs[j][0]  += wvsf[j]  * vx;
                    yvs[j][1]  += wvsf[j]  * vy;
                    yvs[j][2]  += wvsf[j]  * vz;
                    yvvv[j][0] += wvvvf[j] * vx;
                    yvvv[j][1] += wvvvf[j] * vy;
                    yvvv[j][2] += wvvvf[j] * vz;
                }
            }
        }

        // ---- epilogue: fold in x2, write ----
        if (act) {
            const float4 x2v = *(const float4*)(x2 + (size_t)z * 4);
            const float s2  = x2v.x;
            const float v2x = x2v.y;
            const float v2y = x2v.z;
            const float v2z = x2v.w;
            float* orow = out + (size_t)z * 256;
            alignas(16) float os[4];
            alignas(16) float ov[12];
            #pragma unroll
            for (int j = 0; j < 4; ++j) {
                os[j] = a0 * (yss[j] * s2
                      + is3 * (yvvs[j][0] * v2x + yvvs[j][1] * v2y + yvvs[j][2] * v2z));
                const float cx = yvvv[j][1] * v2z - yvvv[j][2] * v2y;
                const float cy = yvvv[j][2] * v2x - yvvv[j][0] * v2z;
                const float cz = yvvv[j][0] * v2y - yvvv[j][1] * v2x;
                ov[3*j+0] = a1 * (ysv[j] * v2x + yvs[j][0] * s2 + is2 * cx);
                ov[3*j+1] = a1 * (ysv[j] * v2y + yvs[j][1] * s2 + is2 * cy);
                ov[3*j+2] = a1 * (ysv[j] * v2z + yvs[j][2] * s2 + is2 * cz);
            }
            *(float4*)(orow + 4*g)           = *(float4*)os;
            *(float4*)(orow + 64 + 12*g + 0) = *(float4*)(ov + 0);
            *(float4*)(orow + 64 + 12*g + 4) = *(float4*)(ov + 4);
            *(float4*)(orow + 64 + 12*g + 8) = *(float4*)(ov + 8);
        }
    }
}

extern "C" void kernel_launch(void* const* d_in, const int* in_sizes, int n_in,
                              void* d_out, int out_size, void* d_ws, size_t ws_size,
                              hipStream_t stream) {
    const float* x1 = (const float*)d_in[0];
    const float* x2 = (const float*)d_in[1];
    const float* w0 = (const float*)d_in[2];   // w_ss_s
    const float* w1 = (const float*)d_in[3];   // w_vv_s
    const float* w2 = (const float*)d_in[4];   // w_sv_v
    const float* w3 = (const float*)d_in[5];   // w_vs_v
    const float* w4 = (const float*)d_in[6];   // w_vv_v
    float* out = (float*)d_out;
    const int n = in_sizes[0] / 256;
    tp_kernel<<<512, BLOCK, 0, stream>>>(x1, x2, w0, w1, w2, w3, w4, out, n);
}